// Round 1
// baseline (1757.564 us; speedup 1.0000x reference)
//
#include <hip/hip_runtime.h>
#include <stdint.h>
#include <stddef.h>

#define N_ 2048
#define D_ 64
#define INNER_ 32
#define HIDDEN_ 2048
#define CLASSES_ 10
#define P_ 2016
#define K_ (P_ * INNER_)      // 64512
#define SPLITK 4
#define KCHUNK (K_ / SPLITK)  // 16128
#define BM 128
#define BN 128
#define BK 32

typedef __bf16 bf16x8 __attribute__((ext_vector_type(8)));
typedef __bf16 bf16x4 __attribute__((ext_vector_type(4)));
typedef float f32x4v __attribute__((ext_vector_type(4)));
typedef float f32x2v __attribute__((ext_vector_type(2)));
typedef __attribute__((address_space(1))) void gvoid_t;
typedef __attribute__((address_space(3))) void lvoid_t;

// ---------------- stage 1: u[n, p*32+i] = relu(x[n,ii]*Wu[p,0,i] + x[n,jj]*Wu[p,1,i] + bu[p,i]) ----
__global__ __launch_bounds__(256) void k_u(const float* __restrict__ x,
                                           const float* __restrict__ Wu,
                                           const float* __restrict__ bu,
                                           __bf16* __restrict__ u) {
  const int n = blockIdx.y;
  const int t = threadIdx.x;
  __shared__ float xs[D_];
  if (t < D_) xs[t] = x[(size_t)n * D_ + t];
  __syncthreads();
  const int k0 = blockIdx.x * 1024 + t * 4;  // 4 consecutive k, same pair p
  const int p  = k0 >> 5;
  const int i0 = k0 & 31;
  // invert row-major triu(k=1) index: row boundaries are exact squares -> exact fp32 sqrt
  int ii = (int)floorf((127.0f - sqrtf(16129.0f - 8.0f * (float)p)) * 0.5f);
  int off = ii * 63 - (ii * (ii - 1)) / 2;
  while (p >= off + (63 - ii)) { off += 63 - ii; ++ii; }  // safety fix-up (normally 0 iters)
  while (p < off)              { --ii; off -= 63 - ii; }
  const int jj = (p - off) + ii + 1;
  const float xi = xs[ii], xj = xs[jj];
  const float4 w0 = *(const float4*)(Wu + (size_t)p * 64 + i0);
  const float4 w1 = *(const float4*)(Wu + (size_t)p * 64 + 32 + i0);
  const float4 bb = *(const float4*)(bu + (size_t)p * 32 + i0);
  bf16x4 r;
  r[0] = (__bf16)fmaxf(fmaf(xi, w0.x, fmaf(xj, w1.x, bb.x)), 0.0f);
  r[1] = (__bf16)fmaxf(fmaf(xi, w0.y, fmaf(xj, w1.y, bb.y)), 0.0f);
  r[2] = (__bf16)fmaxf(fmaf(xi, w0.z, fmaf(xj, w1.z, bb.z)), 0.0f);
  r[3] = (__bf16)fmaxf(fmaf(xi, w0.w, fmaf(xj, w1.w, bb.w)), 0.0f);
  *(bf16x4*)(u + (size_t)n * K_ + k0) = r;
}

// ---------------- stage 2: split-K bf16 MFMA GEMM, partials[kc] = u[:,kc-range] @ Wv[kc-range,:] ----
__global__ __launch_bounds__(256) void k_gemm(const __bf16* __restrict__ A,  // u [N_][K_] bf16
                                              const float* __restrict__ Bv,  // Wv [K_][HIDDEN_] f32
                                              float* __restrict__ part) {    // [SPLITK][N_][HIDDEN_]
  __shared__ __bf16 As[BM][BK];       // 8 KB contiguous (global_load_lds: no padding allowed)
  __shared__ __bf16 BsT[BN][BK + 8];  // row stride 80 B: transpose writes 2-way, frag reads balanced

  const int t    = threadIdx.x;
  const int lane = t & 63;
  const int w    = t >> 6;       // wave 0..3
  const int wm   = w >> 1;       // 2x2 wave grid, each wave 64x64
  const int wn   = w & 1;
  const int l15  = lane & 15;
  const int q    = lane >> 4;    // quad 0..3
  const int bn = blockIdx.x, bm = blockIdx.y, kc = blockIdx.z;
  const int mbase = bm * BM, hbase = bn * BN;

  // B transpose-staging mapping: thread -> (2 h-rows, 8 k's)
  const int n0 = (t & 63) * 2;
  const int kq = t >> 6;

  // fragment read pointers (fixed per lane; tiles reloaded in place)
  const bf16x8* ap[4];
  const bf16x8* bp[4];
#pragma unroll
  for (int mf = 0; mf < 4; ++mf) ap[mf] = (const bf16x8*)&As[wm * 64 + mf * 16 + l15][q * 8];
#pragma unroll
  for (int nf = 0; nf < 4; ++nf) bp[nf] = (const bf16x8*)&BsT[wn * 64 + nf * 16 + l15][q * 8];

  f32x4v acc[4][4] = {};

  const int ksteps = KCHUNK / BK;  // 504
  for (int ks = 0; ks < ksteps; ++ks) {
    const int kbase = kc * KCHUNK + ks * BK;

    // B global loads first (long-latency, no LDS dependency): coalesced 512B/instr
    const float* gb = Bv + (size_t)(kbase + kq * 8) * HIDDEN_ + hbase + n0;
    f32x2v f[8];
#pragma unroll
    for (int qq = 0; qq < 8; ++qq) f[qq] = *(const f32x2v*)(gb + (size_t)qq * HIDDEN_);

    __syncthreads();  // previous iteration's frag reads done before overwriting LDS

    // A: async global->LDS, width 16. LDS dest = wave-uniform base + lane*16.
#pragma unroll
    for (int r = 0; r < 2; ++r) {
      const int flat = r * 256 + t;
      const __bf16* ga = A + (size_t)(mbase + (flat >> 2)) * K_ + kbase + (flat & 3) * 8;
      void* lp = (char*)&As[0][0] + (size_t)(r * 256 + (t & ~63)) * 16;
      __builtin_amdgcn_global_load_lds((gvoid_t*)(uintptr_t)ga,
                                       (lvoid_t*)(uint32_t)(uintptr_t)lp, 16, 0, 0);
    }

    // B: convert fp32->bf16 and write transposed (k-contiguous rows)
    bf16x8 c0, c1;
#pragma unroll
    for (int qq = 0; qq < 8; ++qq) { c0[qq] = (__bf16)f[qq][0]; c1[qq] = (__bf16)f[qq][1]; }
    *(bf16x8*)&BsT[n0][kq * 8]     = c0;
    *(bf16x8*)&BsT[n0 + 1][kq * 8] = c1;

    __syncthreads();  // staging visible (compiler drains vmcnt for global_load_lds)

    bf16x8 av[4], bv4[4];
#pragma unroll
    for (int mf = 0; mf < 4; ++mf) av[mf] = *ap[mf];
#pragma unroll
    for (int nf = 0; nf < 4; ++nf) bv4[nf] = *bp[nf];
#pragma unroll
    for (int mf = 0; mf < 4; ++mf)
#pragma unroll
      for (int nf = 0; nf < 4; ++nf)
        acc[mf][nf] = __builtin_amdgcn_mfma_f32_16x16x32_bf16(av[mf], bv4[nf], acc[mf][nf], 0, 0, 0);
  }

  // epilogue: C/D layout col=lane&15, row=quad*4+reg
  float* op = part + ((size_t)kc * N_ + mbase + wm * 64) * HIDDEN_ + hbase + wn * 64;
#pragma unroll
  for (int mf = 0; mf < 4; ++mf)
#pragma unroll
    for (int nf = 0; nf < 4; ++nf)
#pragma unroll
      for (int r = 0; r < 4; ++r)
        op[(size_t)(mf * 16 + q * 4 + r) * HIDDEN_ + nf * 16 + l15] = acc[mf][nf][r];
}

// ---------------- stage 3: v = relu(sum(partials) + bv) ----------------
__global__ __launch_bounds__(256) void k_reduce(const float* __restrict__ part,
                                                const float* __restrict__ bv,
                                                float* __restrict__ v) {
  const size_t i = ((size_t)blockIdx.x * 256 + threadIdx.x) * 4;
  f32x4v s = *(const f32x4v*)(part + i);
  s += *(const f32x4v*)(part + (size_t)1 * N_ * HIDDEN_ + i);
  s += *(const f32x4v*)(part + (size_t)2 * N_ * HIDDEN_ + i);
  s += *(const f32x4v*)(part + (size_t)3 * N_ * HIDDEN_ + i);
  s += *(const f32x4v*)(bv + (i & (HIDDEN_ - 1)));
  s[0] = fmaxf(s[0], 0.0f);
  s[1] = fmaxf(s[1], 0.0f);
  s[2] = fmaxf(s[2], 0.0f);
  s[3] = fmaxf(s[3], 0.0f);
  *(f32x4v*)(v + i) = s;
}

// ---------------- stage 4: out = v @ Wo + bo (wave per row) ----------------
__global__ __launch_bounds__(256) void k_out(const float* __restrict__ v,
                                             const float* __restrict__ Wo,
                                             const float* __restrict__ bo,
                                             float* __restrict__ out) {
  const int lane = threadIdx.x & 63;
  const int n = blockIdx.x * 4 + (threadIdx.x >> 6);
  float acc[CLASSES_];
#pragma unroll
  for (int c = 0; c < CLASSES_; ++c) acc[c] = 0.0f;
  for (int h0 = lane * 4; h0 < HIDDEN_; h0 += 256) {
    const f32x4v vv = *(const f32x4v*)(v + (size_t)n * HIDDEN_ + h0);
#pragma unroll
    for (int qq = 0; qq < 4; ++qq) {
      const float s = vv[qq];
      const float* wo = Wo + (size_t)(h0 + qq) * CLASSES_;
#pragma unroll
      for (int c = 0; c < CLASSES_; ++c) acc[c] = fmaf(s, wo[c], acc[c]);
    }
  }
#pragma unroll
  for (int c = 0; c < CLASSES_; ++c) {
#pragma unroll
    for (int o = 32; o > 0; o >>= 1) acc[c] += __shfl_down(acc[c], o);
  }
  if (lane == 0) {
#pragma unroll
    for (int c = 0; c < CLASSES_; ++c) out[(size_t)n * CLASSES_ + c] = acc[c] + bo[c];
  }
}

extern "C" void kernel_launch(void* const* d_in, const int* in_sizes, int n_in,
                              void* d_out, int out_size, void* d_ws, size_t ws_size,
                              hipStream_t stream) {
  const float* x  = (const float*)d_in[0];
  const float* Wu = (const float*)d_in[1];
  const float* bu = (const float*)d_in[2];
  const float* Wv = (const float*)d_in[3];
  const float* bv = (const float*)d_in[4];
  const float* Wo = (const float*)d_in[5];
  const float* bo = (const float*)d_in[6];
  float* out = (float*)d_out;

  char* ws = (char*)d_ws;
  __bf16* u   = (__bf16*)ws;                                   // 264,241,152 B
  float* part = (float*)(ws + (size_t)N_ * K_ * 2);            // 67,108,864 B
  float* v    = (float*)(ws + (size_t)N_ * K_ * 2 +
                         (size_t)SPLITK * N_ * HIDDEN_ * 4);   // 16,777,216 B
  // total ws use: 348,127,232 B

  k_u<<<dim3(K_ / 1024, N_), 256, 0, stream>>>(x, Wu, bu, u);
  k_gemm<<<dim3(HIDDEN_ / BN, N_ / BM, SPLITK), 256, 0, stream>>>(u, Wv, part);
  k_reduce<<<dim3((N_ * HIDDEN_) / 1024), 256, 0, stream>>>(part, bv, v);
  k_out<<<dim3(N_ / 4), 256, 0, stream>>>(v, Wo, bo, out);
}